// Round 1
// baseline (121.713 us; speedup 1.0000x reference)
//
#include <hip/hip_runtime.h>
#include <math.h>

#define PH 7
#define PW 7
#define B_ 4
#define C_ 256
#define H_ 50
#define W_ 50
#define R_ 256
#define S_ (H_ * W_)  // 2500

// Transpose features (B,C,H,W) -> (B,H,W,C) so channels are contiguous.
// Standard 32x32 LDS tile transpose per batch: (C, S) -> (S, C).
__global__ void transpose_chw_hwc(const float* __restrict__ in, float* __restrict__ out) {
    __shared__ float tile[32][33];  // +1 pad: no bank conflicts
    const int b  = blockIdx.z;
    const int s0 = blockIdx.x * 32;
    const int c0 = blockIdx.y * 32;
    const float* inb  = in  + (size_t)b * C_ * S_;
    float*       outb = out + (size_t)b * S_ * C_;
    const int tx = threadIdx.x;
    #pragma unroll
    for (int i = threadIdx.y; i < 32; i += 8) {
        const int s = s0 + tx;
        if (s < S_) tile[i][tx] = inb[(size_t)(c0 + i) * S_ + s];  // C_=256 is a multiple of 32
    }
    __syncthreads();
    #pragma unroll
    for (int i = threadIdx.y; i < 32; i += 8) {
        const int s = s0 + i;
        if (s < S_) outb[(size_t)s * C_ + (c0 + tx)] = tile[tx][i];
    }
}

// One block per (r, ph, pw). 64 lanes; lane owns 4 channels via float4.
// Coalesced 1 KiB/wave loads from the transposed layout.
__global__ void roi_pool_t(const float* __restrict__ ft, const int* __restrict__ rois,
                           float* __restrict__ out) {
    const int bx   = blockIdx.x;
    const int r    = bx / (PH * PW);
    const int cell = bx % (PH * PW);
    const int ph   = cell / PW;
    const int pw   = cell % PW;
    const int lane = threadIdx.x;  // 0..63

    const int* roi = rois + r * 5;
    const int b  = roi[0];
    const int x1 = roi[1] >> 4;   // floor(v * 0.0625), v >= 0
    const int y1 = roi[2] >> 4;
    const int x2 = roi[3] >> 4;
    const int y2 = roi[4] >> 4;
    const int h = y2 - y1 + 1;
    const int w = x2 - x1 + 1;

    const int sh = y1 + (ph * h) / PH;
    const int eh = y1 + ((ph + 1) * h + PH - 1) / PH;
    const int sw = x1 + (pw * w) / PW;
    const int ew = x1 + ((pw + 1) * w + PW - 1) / PW;

    float4 acc = make_float4(-INFINITY, -INFINITY, -INFINITY, -INFINITY);
    const float* base = ft + (size_t)b * S_ * C_ + 4 * lane;
    for (int y = sh; y < eh; ++y) {
        const float* rowp = base + (size_t)(y * W_) * C_;
        for (int x = sw; x < ew; ++x) {
            const float4 v = *(const float4*)(rowp + (size_t)x * C_);
            acc.x = fmaxf(acc.x, v.x);
            acc.y = fmaxf(acc.y, v.y);
            acc.z = fmaxf(acc.z, v.z);
            acc.w = fmaxf(acc.w, v.w);
        }
    }

    const int c = 4 * lane;
    const size_t o = (((size_t)r * C_ + c) * PH + ph) * PW + pw;
    out[o]               = acc.x;
    out[o + PH * PW]     = acc.y;
    out[o + 2 * PH * PW] = acc.z;
    out[o + 3 * PH * PW] = acc.w;
}

// Fallback if workspace is too small for the transposed copy: lane = channel,
// scalar (uncoalesced) loads straight from (B,C,H,W).
__global__ void roi_pool_direct(const float* __restrict__ f, const int* __restrict__ rois,
                                float* __restrict__ out) {
    const int bx   = blockIdx.x;
    const int r    = bx / (PH * PW);
    const int cell = bx % (PH * PW);
    const int ph   = cell / PW;
    const int pw   = cell % PW;
    const int c    = threadIdx.x;  // 0..255

    const int* roi = rois + r * 5;
    const int b  = roi[0];
    const int x1 = roi[1] >> 4;
    const int y1 = roi[2] >> 4;
    const int x2 = roi[3] >> 4;
    const int y2 = roi[4] >> 4;
    const int h = y2 - y1 + 1;
    const int w = x2 - x1 + 1;

    const int sh = y1 + (ph * h) / PH;
    const int eh = y1 + ((ph + 1) * h + PH - 1) / PH;
    const int sw = x1 + (pw * w) / PW;
    const int ew = x1 + ((pw + 1) * w + PW - 1) / PW;

    float acc = -INFINITY;
    const float* base = f + ((size_t)(b * C_ + c)) * S_;
    for (int y = sh; y < eh; ++y)
        for (int x = sw; x < ew; ++x)
            acc = fmaxf(acc, base[y * W_ + x]);

    out[(((size_t)r * C_ + c) * PH + ph) * PW + pw] = acc;
}

extern "C" void kernel_launch(void* const* d_in, const int* in_sizes, int n_in,
                              void* d_out, int out_size, void* d_ws, size_t ws_size,
                              hipStream_t stream) {
    const float* features = (const float*)d_in[0];
    const int*   rois     = (const int*)d_in[1];
    float*       out      = (float*)d_out;

    const size_t need = (size_t)B_ * S_ * C_ * sizeof(float);  // 10.24 MB
    if (ws_size >= need) {
        float* ft = (float*)d_ws;
        dim3 tgrid((S_ + 31) / 32, C_ / 32, B_);
        transpose_chw_hwc<<<tgrid, dim3(32, 8), 0, stream>>>(features, ft);
        roi_pool_t<<<R_ * PH * PW, 64, 0, stream>>>(ft, rois, out);
    } else {
        roi_pool_direct<<<R_ * PH * PW, C_, 0, stream>>>(features, rois, out);
    }
}